// Round 2
// baseline (233.474 us; speedup 1.0000x reference)
//
#include <hip/hip_runtime.h>

#define BB 2
#define NN 16
#define LQ 512
#define DKk 64
#define DVv 64
#define DDd 128
#define H2 256
#define NEG_INF -1e9f
#define CAP 131072

// ---------------------------------------------------------------------------
// Stage 1: 8 rows per block (reuses each W1 load 8x; W1 L2 traffic 33 MB).
//   half 0: U[row,g] = b1[g] + sum_f d0[row,f]*W1[f,g]      (fp64 + fp32)
//   half 1: W[row,g] =         sum_f d1[row,f]*W1[128+f,g]
// ---------------------------------------------------------------------------
__global__ __launch_bounds__(256) void mlp_stage1(
    const float* __restrict__ d0, const float* __restrict__ d1,
    const float* __restrict__ W1, const float* __restrict__ b1,
    double* __restrict__ U64, double* __restrict__ W64,
    float* __restrict__ U32, float* __restrict__ W32)
{
    __shared__ float drow[8][DDd];
    int gid = blockIdx.x;            // half(2) x rowgroup(128)
    int half = gid >> 7;
    int r0 = (gid & 127) * 8;        // rows r0..r0+7 of 1024
    const float* din = half ? d1 : d0;
    int w1off = half ? DDd : 0;
    double* o64 = half ? W64 : U64;
    float* o32 = half ? W32 : U32;
    int t = threadIdx.x;
    {   // stage 8 rows x 128 f (4 floats/thread)
        int rr = t >> 5, f4 = t & 31;
        *(float4*)&drow[rr][f4 * 4] =
            *(const float4*)(din + (size_t)(r0 + rr) * DDd + f4 * 4);
    }
    __syncthreads();
    int g = t;
    double acc[8] = {};
#pragma unroll 2
    for (int f = 0; f < DDd; f += 4) {
        double w0 = (double)W1[(w1off + f + 0) * H2 + g];
        double w1 = (double)W1[(w1off + f + 1) * H2 + g];
        double w2 = (double)W1[(w1off + f + 2) * H2 + g];
        double w3 = (double)W1[(w1off + f + 3) * H2 + g];
#pragma unroll
        for (int r = 0; r < 8; ++r) {
            float4 dr = *(const float4*)&drow[r][f];
            acc[r] = fma((double)dr.x, w0, acc[r]);
            acc[r] = fma((double)dr.y, w1, acc[r]);
            acc[r] = fma((double)dr.z, w2, acc[r]);
            acc[r] = fma((double)dr.w, w3, acc[r]);
        }
    }
    double bb = half ? 0.0 : (double)b1[g];
#pragma unroll
    for (int r = 0; r < 8; ++r) {
        double a = acc[r] + bb;
        o64[(size_t)(r0 + r) * H2 + g] = a;
        o32[(size_t)(r0 + r) * H2 + g] = (float)a;
    }
}

// ---------------------------------------------------------------------------
// dec_partial v4: g-split x2 for occupancy. Grid 1024 = gh(2) x b(2) x it(32)
// x jt(8) -> 4 blocks/CU, 16 waves/CU (prev: 2 blocks/CU, 8 waves, 17.8% occ,
// VALUBusy 11% => latency-bound). Each block: 16i x 64j x 128g partial sums.
// LDS ~23 KB (gc chunk 64). Inner loop register-double-buffered: prefetch
// next 6 float4 while computing current 48 FMAs; last step peeled.
// fp32 sum order changed (two ascending halves) — safe: error ~1e-5 vs the
// 2e-2 fp64-recheck band; all flagged pairs get exact fp64 signs.
// ---------------------------------------------------------------------------
#define FMABLOCK(u4, gv4, w0, w1, w2, w3)                          \
    do {                                                           \
        acc[0] = fmaf(fmaxf(u4.x + w0.x, 0.f), gv4.x, acc[0]);     \
        acc[1] = fmaf(fmaxf(u4.x + w0.y, 0.f), gv4.x, acc[1]);     \
        acc[2] = fmaf(fmaxf(u4.x + w0.z, 0.f), gv4.x, acc[2]);     \
        acc[3] = fmaf(fmaxf(u4.x + w0.w, 0.f), gv4.x, acc[3]);     \
        acc[0] = fmaf(fmaxf(u4.y + w1.x, 0.f), gv4.y, acc[0]);     \
        acc[1] = fmaf(fmaxf(u4.y + w1.y, 0.f), gv4.y, acc[1]);     \
        acc[2] = fmaf(fmaxf(u4.y + w1.z, 0.f), gv4.y, acc[2]);     \
        acc[3] = fmaf(fmaxf(u4.y + w1.w, 0.f), gv4.y, acc[3]);     \
        acc[0] = fmaf(fmaxf(u4.z + w2.x, 0.f), gv4.z, acc[0]);     \
        acc[1] = fmaf(fmaxf(u4.z + w2.y, 0.f), gv4.z, acc[1]);     \
        acc[2] = fmaf(fmaxf(u4.z + w2.z, 0.f), gv4.z, acc[2]);     \
        acc[3] = fmaf(fmaxf(u4.z + w2.w, 0.f), gv4.z, acc[3]);     \
        acc[0] = fmaf(fmaxf(u4.w + w3.x, 0.f), gv4.w, acc[0]);     \
        acc[1] = fmaf(fmaxf(u4.w + w3.y, 0.f), gv4.w, acc[1]);     \
        acc[2] = fmaf(fmaxf(u4.w + w3.z, 0.f), gv4.w, acc[2]);     \
        acc[3] = fmaf(fmaxf(u4.w + w3.w, 0.f), gv4.w, acc[3]);     \
    } while (0)

__global__ __launch_bounds__(256, 4) void dec_partial(
    const float* __restrict__ U32, const float* __restrict__ W32,
    const float* __restrict__ W2,
    float* __restrict__ part)
{
    __shared__ __align__(16) float Us[16][68];    // [i][g-chunk]
    __shared__ __align__(16) float Wt[64][68];    // [g][j]  (transposed)
    __shared__ __align__(16) float gvs[128];
    int bid = blockIdx.x;            // gh(2) x b(2) x it(32) x jt(8)
    int gh = bid >> 9;
    int b  = (bid >> 8) & 1;
    int i0 = ((bid >> 3) & 31) * 16;
    int j0 = (bid & 7) * 64;
    int g0 = gh * 128;
    int t = threadIdx.x;
    if (t < 128) gvs[t] = W2[(g0 + t) * 2 + 1] - W2[(g0 + t) * 2];
    int ti = t >> 4, tj4 = (t & 15) * 4;
    float acc[4] = {0.f, 0.f, 0.f, 0.f};
    for (int gc = 0; gc < 128; gc += 64) {
        __syncthreads();
        {   // stage U: 16 rows x 64 g, one float4/thread
            int ui = t >> 4, gq = t & 15;
            *(float4*)&Us[ui][gq * 4] =
                *(const float4*)(U32 + ((size_t)(b * LQ) + i0 + ui) * H2 + g0 + gc + gq * 4);
        }
        {   // stage W transposed: 64 j-rows x 64 g (2-way writes = free)
            int wj = t >> 2;
            const float* src = W32 + ((size_t)(b * LQ) + j0 + wj) * H2 + g0 + gc;
#pragma unroll
            for (int it = 0; it < 4; ++it) {
                int gq = (t & 3) + it * 4;
                float4 w4 = *(const float4*)(src + gq * 4);
                Wt[gq * 4 + 0][wj] = w4.x;
                Wt[gq * 4 + 1][wj] = w4.y;
                Wt[gq * 4 + 2][wj] = w4.z;
                Wt[gq * 4 + 3][wj] = w4.w;
            }
        }
        __syncthreads();
        float4 u_c  = *(const float4*)&Us[ti][0];
        float4 gv_c = *(const float4*)&gvs[gc];
        float4 w0_c = *(const float4*)&Wt[0][tj4];
        float4 w1_c = *(const float4*)&Wt[1][tj4];
        float4 w2_c = *(const float4*)&Wt[2][tj4];
        float4 w3_c = *(const float4*)&Wt[3][tj4];
#pragma unroll 3
        for (int gg = 0; gg < 60; gg += 4) {
            float4 u_n  = *(const float4*)&Us[ti][gg + 4];
            float4 gv_n = *(const float4*)&gvs[gc + gg + 4];
            float4 w0_n = *(const float4*)&Wt[gg + 4][tj4];
            float4 w1_n = *(const float4*)&Wt[gg + 5][tj4];
            float4 w2_n = *(const float4*)&Wt[gg + 6][tj4];
            float4 w3_n = *(const float4*)&Wt[gg + 7][tj4];
            FMABLOCK(u_c, gv_c, w0_c, w1_c, w2_c, w3_c);
            u_c = u_n; gv_c = gv_n;
            w0_c = w0_n; w1_c = w1_n; w2_c = w2_n; w3_c = w3_n;
        }
        FMABLOCK(u_c, gv_c, w0_c, w1_c, w2_c, w3_c);
    }
    int row = b * LQ + i0 + ti;
    *(float4*)&part[((size_t)gh * 1024 + row) * LQ + j0 + tj4] =
        make_float4(acc[0], acc[1], acc[2], acc[3]);
}

// ---------------------------------------------------------------------------
// Combine the two g-halves: gap = p0 + p1 + bias; write dec; flag |gap|<2e-2.
// ---------------------------------------------------------------------------
__global__ __launch_bounds__(256) void dec_combine(
    const float* __restrict__ part, const float* __restrict__ b2,
    float* __restrict__ dec_out, int* __restrict__ count, int* __restrict__ list)
{
    int idx = blockIdx.x * 256 + threadIdx.x;    // 0..131071 (float4 units)
    float bias = b2[1] - b2[0];
    int row = idx >> 7;                          // 0..1023
    int jb = (idx & 127) * 4;
    float4 p0 = *(const float4*)&part[(size_t)row * LQ + jb];
    float4 p1 = *(const float4*)&part[((size_t)1024 + row) * LQ + jb];
    float g0 = p0.x + p1.x + bias;
    float g1 = p0.y + p1.y + bias;
    float g2 = p0.z + p1.z + bias;
    float g3 = p0.w + p1.w + bias;
    float4 dv;
    dv.x = g0 > 0.f ? 1.f : 0.f; dv.y = g1 > 0.f ? 1.f : 0.f;
    dv.z = g2 > 0.f ? 1.f : 0.f; dv.w = g3 > 0.f ? 1.f : 0.f;
    *(float4*)&dec_out[(size_t)row * LQ + jb] = dv;
    if (fabsf(g0) < 2e-2f) { int ix = atomicAdd(count, 1); if (ix < CAP) list[ix] = (row << 9) | jb; }
    if (fabsf(g1) < 2e-2f) { int ix = atomicAdd(count, 1); if (ix < CAP) list[ix] = (row << 9) | (jb + 1); }
    if (fabsf(g2) < 2e-2f) { int ix = atomicAdd(count, 1); if (ix < CAP) list[ix] = (row << 9) | (jb + 2); }
    if (fabsf(g3) < 2e-2f) { int ix = atomicAdd(count, 1); if (ix < CAP) list[ix] = (row << 9) | (jb + 3); }
}

// ---------------------------------------------------------------------------
// Exact fp64 gap for every flagged pair; writes fp64-sign decision.
// Tie (gap == 0) -> decision 0, matching np.argmax first-max semantics.
// ---------------------------------------------------------------------------
__global__ __launch_bounds__(256) void gap64_kernel(
    const double* __restrict__ U64, const double* __restrict__ W64,
    const float* __restrict__ W2, const float* __restrict__ b2,
    const int* __restrict__ count, const int* __restrict__ list,
    float* __restrict__ dec_out)
{
    int n = *count; if (n > CAP) n = CAP;
    int gw = (blockIdx.x * 256 + threadIdx.x) >> 6;
    int lane = threadIdx.x & 63;
    int nw = (gridDim.x * 256) >> 6;
    for (int idx = gw; idx < n; idx += nw) {
        int pij = list[idx];
        int j = pij & (LQ - 1);
        int row = pij >> 9;
        int b = row >> 9;
        const double* u = U64 + (size_t)row * H2;
        const double* w = W64 + ((size_t)(b * LQ) + j) * H2;
        double acc = 0.0;
        for (int g = lane; g < H2; g += 64) {
            double tv = u[g] + w[g];
            tv = tv > 0.0 ? tv : 0.0;
            acc = fma(tv, (double)W2[g * 2 + 1] - (double)W2[g * 2 + 0], acc);
        }
#pragma unroll
        for (int off = 32; off; off >>= 1) acc += __shfl_xor(acc, off, 64);
        if (lane == 0) {
            acc += (double)b2[1] - (double)b2[0];
            dec_out[(size_t)row * LQ + j] = acc > 0.0 ? 1.f : 0.f;
        }
    }
}

// ---------------------------------------------------------------------------
// Fused attention v2: grid 512 (32 bn x 16 i-tiles of 32 rows, 2 blocks/CU).
// ---------------------------------------------------------------------------
__global__ __launch_bounds__(256) void fused_attn(
    const float* __restrict__ q, const float* __restrict__ k,
    const float* __restrict__ v, const float* __restrict__ dec,
    float* __restrict__ attn, float* __restrict__ out)
{
    __shared__ __align__(16) float smem[10752];   // 43 KB, phase-overlaid
    float* qT = smem;            // [64][36]   kk-major
    float* kT = smem + 2304;     // [64][132]  kk-major
    float* Ps = smem;            // [32][65]   i-major  (PV phase)
    float* Vs = smem + 2112;     // [64][68]   j-major  (PV phase)
    int bid = blockIdx.x;
    int bn = bid >> 4;
    int i0 = (bid & 15) * 32;
    int b = bn >> 4;
    int t = threadIdx.x;

    {   // stage qT (transpose): i = t>>3, kkq = (t&7)+8*it
        int qi = t >> 3;
        const float* src = q + ((size_t)bn * LQ + i0 + qi) * DKk;
#pragma unroll
        for (int it = 0; it < 2; ++it) {
            int kkq = (t & 7) + it * 8;
            float4 t4 = *(const float4*)(src + kkq * 4);
            qT[(kkq * 4 + 0) * 36 + qi] = t4.x;
            qT[(kkq * 4 + 1) * 36 + qi] = t4.y;
            qT[(kkq * 4 + 2) * 36 + qi] = t4.z;
            qT[(kkq * 4 + 3) * 36 + qi] = t4.w;
        }
    }
    int tiq = t >> 5;            // 0..7  -> i = tiq*4 + r
    int tjq = t & 31;            // 0..31 -> j = c*128 + tjq*4 + cc
    float s[4][4][4];

#pragma unroll
    for (int c = 0; c < 4; ++c) {
        __syncthreads();
        {   // stage kT (transpose): j = (t>>2)+(it&1)*64, kkq = (t&3)+(it>>1)*4
            int kj = t >> 2;
#pragma unroll
            for (int it = 0; it < 8; ++it) {
                int jj = kj + (it & 1) * 64;
                int kkq = (t & 3) + (it >> 1) * 4;
                float4 t4 = *(const float4*)(k + ((size_t)bn * LQ + c * 128 + jj) * DKk + kkq * 4);
                kT[(kkq * 4 + 0) * 132 + jj] = t4.x;
                kT[(kkq * 4 + 1) * 132 + jj] = t4.y;
                kT[(kkq * 4 + 2) * 132 + jj] = t4.z;
                kT[(kkq * 4 + 3) * 132 + jj] = t4.w;
            }
        }
        __syncthreads();
        float acc[4][4] = {};
#pragma unroll 8
        for (int kk = 0; kk < 64; ++kk) {
            float4 a  = *(const float4*)&qT[kk * 36 + tiq * 4];
            float4 bb = *(const float4*)&kT[kk * 132 + tjq * 4];
            acc[0][0] = fmaf(a.x, bb.x, acc[0][0]); acc[0][1] = fmaf(a.x, bb.y, acc[0][1]);
            acc[0][2] = fmaf(a.x, bb.z, acc[0][2]); acc[0][3] = fmaf(a.x, bb.w, acc[0][3]);
            acc[1][0] = fmaf(a.y, bb.x, acc[1][0]); acc[1][1] = fmaf(a.y, bb.y, acc[1][1]);
            acc[1][2] = fmaf(a.y, bb.z, acc[1][2]); acc[1][3] = fmaf(a.y, bb.w, acc[1][3]);
            acc[2][0] = fmaf(a.z, bb.x, acc[2][0]); acc[2][1] = fmaf(a.z, bb.y, acc[2][1]);
            acc[2][2] = fmaf(a.z, bb.z, acc[2][2]); acc[2][3] = fmaf(a.z, bb.w, acc[2][3]);
            acc[3][0] = fmaf(a.w, bb.x, acc[3][0]); acc[3][1] = fmaf(a.w, bb.y, acc[3][1]);
            acc[3][2] = fmaf(a.w, bb.z, acc[3][2]); acc[3][3] = fmaf(a.w, bb.w, acc[3][3]);
        }
#pragma unroll
        for (int r = 0; r < 4; ++r) {
            float4 m4 = *(const float4*)&dec[((size_t)(b * LQ) + i0 + tiq * 4 + r) * LQ + c * 128 + tjq * 4];
            s[c][r][0] = m4.x != 0.f ? acc[r][0] * 0.125f : NEG_INF;
            s[c][r][1] = m4.y != 0.f ? acc[r][1] * 0.125f : NEG_INF;
            s[c][r][2] = m4.z != 0.f ? acc[r][2] * 0.125f : NEG_INF;
            s[c][r][3] = m4.w != 0.f ? acc[r][3] * 0.125f : NEG_INF;
        }
    }
    // softmax over 512 j per row (width-32 shuffle groups = tjq)
#pragma unroll
    for (int r = 0; r < 4; ++r) {
        float m = NEG_INF;
#pragma unroll
        for (int c = 0; c < 4; ++c)
#pragma unroll
            for (int cc = 0; cc < 4; ++cc) m = fmaxf(m, s[c][r][cc]);
#pragma unroll
        for (int off = 1; off < 32; off <<= 1) m = fmaxf(m, __shfl_xor(m, off, 32));
        float sum = 0.f;
#pragma unroll
        for (int c = 0; c < 4; ++c)
#pragma unroll
            for (int cc = 0; cc < 4; ++cc) {
                float e = __expf(s[c][r][cc] - m);
                s[c][r][cc] = e; sum += e;
            }
#pragma unroll
        for (int off = 1; off < 32; off <<= 1) sum += __shfl_xor(sum, off, 32);
        float inv = 1.f / sum;
#pragma unroll
        for (int c = 0; c < 4; ++c)
#pragma unroll
            for (int cc = 0; cc < 4; ++cc) s[c][r][cc] *= inv;
    }
#pragma unroll
    for (int c = 0; c < 4; ++c)
#pragma unroll
        for (int r = 0; r < 4; ++r) {
            float4 wv = make_float4(s[c][r][0], s[c][r][1], s[c][r][2], s[c][r][3]);
            *(float4*)&attn[((size_t)bn * LQ + i0 + tiq * 4 + r) * LQ + c * 128 + tjq * 4] = wv;
        }
    // ---- PV over eight 64-j chunks ----
    int tio = t >> 4;            // 0..15 -> i = tio*2 + rr
    int tdo = t & 15;            // 0..15 -> d = tdo*4
    float o[2][4] = {};
#pragma unroll
    for (int c8 = 0; c8 < 8; ++c8) {
        __syncthreads();
        if ((tjq >> 4) == (c8 & 1)) {      // this thread's s covers this chunk
            int jl4 = tjq & 15;
            int c = c8 >> 1;
#pragma unroll
            for (int r = 0; r < 4; ++r)
#pragma unroll
                for (int cc = 0; cc < 4; ++cc)
                    Ps[(tiq * 4 + r) * 65 + jl4 * 4 + cc] = s[c][r][cc];
        }
        {   // stage Vs: j = t>>2, dq = (t&3)+4*it
            int vj = t >> 2;
#pragma unroll
            for (int it = 0; it < 4; ++it) {
                int dq = (t & 3) + it * 4;
                *(float4*)&Vs[vj * 68 + dq * 4] =
                    *(const float4*)(v + ((size_t)bn * LQ + c8 * 64 + vj) * DVv + dq * 4);
            }
        }
        __syncthreads();
#pragma unroll 8
        for (int jj = 0; jj < 64; ++jj) {
            float p0 = Ps[(tio * 2 + 0) * 65 + jj];
            float p1 = Ps[(tio * 2 + 1) * 65 + jj];
            float4 v4 = *(const float4*)&Vs[jj * 68 + tdo * 4];
            o[0][0] = fmaf(p0, v4.x, o[0][0]); o[0][1] = fmaf(p0, v4.y, o[0][1]);
            o[0][2] = fmaf(p0, v4.z, o[0][2]); o[0][3] = fmaf(p0, v4.w, o[0][3]);
            o[1][0] = fmaf(p1, v4.x, o[1][0]); o[1][1] = fmaf(p1, v4.y, o[1][1]);
            o[1][2] = fmaf(p1, v4.z, o[1][2]); o[1][3] = fmaf(p1, v4.w, o[1][3]);
        }
    }
#pragma unroll
    for (int rr = 0; rr < 2; ++rr)
        *(float4*)&out[((size_t)bn * LQ + i0 + tio * 2 + rr) * DVv + tdo * 4] =
            make_float4(o[rr][0], o[rr][1], o[rr][2], o[rr][3]);
}

// ---------------------------------------------------------------------------
extern "C" void kernel_launch(void* const* d_in, const int* in_sizes, int n_in,
                              void* d_out, int out_size, void* d_ws, size_t ws_size,
                              hipStream_t stream)
{
    const float* q  = (const float*)d_in[0];
    const float* k  = (const float*)d_in[1];
    const float* v  = (const float*)d_in[2];
    const float* d0 = (const float*)d_in[3];
    const float* d1 = (const float*)d_in[4];
    const float* W1 = (const float*)d_in[5];
    const float* b1 = (const float*)d_in[6];
    const float* W2 = (const float*)d_in[7];
    const float* b2 = (const float*)d_in[8];

    float* out  = (float*)d_out;                                  // [2,16,512,64]
    float* attn = out + (size_t)BB * NN * LQ * DVv;               // [2,16,512,512]
    float* dec  = attn + (size_t)BB * NN * LQ * LQ;               // [2,1,512,512]

    // Scratch inside the attn region (32 MB); fully consumed before
    // fused_attn overwrites every attn element (same stream => ordered).
    char* scratch = (char*)attn;
    double* U64 = (double*)(scratch);                             // 0..2 MB
    double* W64 = (double*)(scratch + (2u << 20));                // 2..4 MB
    float*  U32 = (float*) (scratch + (4u << 20));                // 4..5 MB
    float*  W32 = (float*) (scratch + (5u << 20));                // 5..6 MB
    int* count  = (int*)   (scratch + (6u << 20));                // 4 B
    int* list   = (int*)   (scratch + (6u << 20) + 4096);         // 512 KB
    float* part = (float*) (scratch + (7u << 20));                // 7..11 MB

    hipMemsetAsync(count, 0, sizeof(int), stream);
    mlp_stage1<<<256, 256, 0, stream>>>(d0, d1, W1, b1, U64, W64, U32, W32);
    dec_partial<<<1024, 256, 0, stream>>>(U32, W32, W2, part);
    dec_combine<<<512, 256, 0, stream>>>(part, b2, dec, count, list);
    gap64_kernel<<<256, 256, 0, stream>>>(U64, W64, W2, b2, count, list, dec);
    fused_attn<<<512, 256, 0, stream>>>(q, k, v, dec, attn, out);
}

// Round 3
// 228.787 us; speedup vs baseline: 1.0205x; 1.0205x over previous
//
#include <hip/hip_runtime.h>

#define BB 2
#define NN 16
#define LQ 512
#define DKk 64
#define DVv 64
#define DDd 128
#define H2 256
#define NEG_INF -1e9f
#define CAP 131072

// ---------------------------------------------------------------------------
// Stage 1: 8 rows per block (reuses each W1 load 8x).
//   half 0: U[row,g] = b1[g] + sum_f d0[row,f]*W1[f,g]      (fp64 + fp32)
//   half 1: W[row,g] =         sum_f d1[row,f]*W1[128+f,g]
// Block 0 thread 0 also zeroes the ambiguous-pair counter (memset folded in).
// ---------------------------------------------------------------------------
__global__ __launch_bounds__(256) void mlp_stage1(
    const float* __restrict__ d0, const float* __restrict__ d1,
    const float* __restrict__ W1, const float* __restrict__ b1,
    double* __restrict__ U64, double* __restrict__ W64,
    float* __restrict__ U32, float* __restrict__ W32,
    int* __restrict__ count)
{
    __shared__ float drow[8][DDd];
    int gid = blockIdx.x;            // half(2) x rowgroup(128)
    int half = gid >> 7;
    int r0 = (gid & 127) * 8;        // rows r0..r0+7 of 1024
    const float* din = half ? d1 : d0;
    int w1off = half ? DDd : 0;
    double* o64 = half ? W64 : U64;
    float* o32 = half ? W32 : U32;
    int t = threadIdx.x;
    if (gid == 0 && t == 0) *count = 0;
    {   // stage 8 rows x 128 f (4 floats/thread)
        int rr = t >> 5, f4 = t & 31;
        *(float4*)&drow[rr][f4 * 4] =
            *(const float4*)(din + (size_t)(r0 + rr) * DDd + f4 * 4);
    }
    __syncthreads();
    int g = t;
    double acc[8] = {};
#pragma unroll 2
    for (int f = 0; f < DDd; f += 4) {
        double w0 = (double)W1[(w1off + f + 0) * H2 + g];
        double w1 = (double)W1[(w1off + f + 1) * H2 + g];
        double w2 = (double)W1[(w1off + f + 2) * H2 + g];
        double w3 = (double)W1[(w1off + f + 3) * H2 + g];
#pragma unroll
        for (int r = 0; r < 8; ++r) {
            float4 dr = *(const float4*)&drow[r][f];
            acc[r] = fma((double)dr.x, w0, acc[r]);
            acc[r] = fma((double)dr.y, w1, acc[r]);
            acc[r] = fma((double)dr.z, w2, acc[r]);
            acc[r] = fma((double)dr.w, w3, acc[r]);
        }
    }
    double bb = half ? 0.0 : (double)b1[g];
#pragma unroll
    for (int r = 0; r < 8; ++r) {
        double a = acc[r] + bb;
        o64[(size_t)(r0 + r) * H2 + g] = a;
        o32[(size_t)(r0 + r) * H2 + g] = (float)a;
    }
}

// ---------------------------------------------------------------------------
// dec_full v5: ONE kernel for the whole decision plane (R2's split added a
// 4 MB round-trip + an extra dispatch whose 61 us was all overhead/latency).
// Grid 1024 = b(2) x it(32) x jt(16): tile 16i x 32j x 256g, 4 blocks/CU,
// 16 waves/CU (R1 had 2 blocks/CU, 11% VALUBusy => latency-bound).
// LDS 14 KB: Us[16][68], Ws[32][68] un-transposed; per-thread float4 reads
// along g. Thread owns j-pair {tj, tj+16}: 16 distinct Ws rows/wave spread
// over 8 bank-offsets (stride 272 B) -> structural-minimum LDS phases.
// Inner loop register double-buffered: 4 b128 + 24 VALU per 4-g step.
// Ascending-g single-acc fp32 chain; |gap|<2e-2 flagged for fp64 recheck.
// ---------------------------------------------------------------------------
__global__ __launch_bounds__(256, 4) void dec_full(
    const float* __restrict__ U32, const float* __restrict__ W32,
    const float* __restrict__ W2, const float* __restrict__ b2,
    float* __restrict__ dec_out, int* __restrict__ count, int* __restrict__ list)
{
    __shared__ __align__(16) float Us[16][68];    // [i][g-chunk 64]
    __shared__ __align__(16) float Ws[32][68];    // [j][g-chunk 64]
    __shared__ __align__(16) float gvs[H2];
    int bid = blockIdx.x;            // b(2) x it(32) x jt(16)
    int b  = bid >> 9;
    int i0 = ((bid >> 4) & 31) * 16;
    int j0 = (bid & 15) * 32;
    int t = threadIdx.x;
    gvs[t] = W2[t * 2 + 1] - W2[t * 2];
    float bias = b2[1] - b2[0];
    int ti = t >> 4, tj = t & 15;    // i = i0+ti; j in {j0+tj, j0+tj+16}
    float acc0 = 0.f, acc1 = 0.f;
    for (int gc = 0; gc < H2; gc += 64) {
        __syncthreads();
        {   // stage U: 16 rows x 16 float4, 1/thread, coalesced
            int ui = t >> 4, gq = t & 15;
            *(float4*)&Us[ui][gq * 4] =
                *(const float4*)(U32 + ((size_t)(b * LQ) + i0 + ui) * H2 + gc + gq * 4);
        }
        {   // stage W: 32 rows x 16 float4, 2/thread, coalesced
            int wj = t >> 3, gq = t & 7;
            const float* src = W32 + ((size_t)(b * LQ) + j0 + wj) * H2 + gc;
            *(float4*)&Ws[wj][gq * 4] = *(const float4*)(src + gq * 4);
            *(float4*)&Ws[wj][(gq + 8) * 4] = *(const float4*)(src + (gq + 8) * 4);
        }
        __syncthreads();
        float4 u_c  = *(const float4*)&Us[ti][0];
        float4 gv_c = *(const float4*)&gvs[gc];
        float4 wA_c = *(const float4*)&Ws[tj][0];
        float4 wB_c = *(const float4*)&Ws[tj + 16][0];
#pragma unroll 5
        for (int gg = 0; gg < 60; gg += 4) {
            float4 u_n  = *(const float4*)&Us[ti][gg + 4];
            float4 gv_n = *(const float4*)&gvs[gc + gg + 4];
            float4 wA_n = *(const float4*)&Ws[tj][gg + 4];
            float4 wB_n = *(const float4*)&Ws[tj + 16][gg + 4];
            acc0 = fmaf(fmaxf(u_c.x + wA_c.x, 0.f), gv_c.x, acc0);
            acc1 = fmaf(fmaxf(u_c.x + wB_c.x, 0.f), gv_c.x, acc1);
            acc0 = fmaf(fmaxf(u_c.y + wA_c.y, 0.f), gv_c.y, acc0);
            acc1 = fmaf(fmaxf(u_c.y + wB_c.y, 0.f), gv_c.y, acc1);
            acc0 = fmaf(fmaxf(u_c.z + wA_c.z, 0.f), gv_c.z, acc0);
            acc1 = fmaf(fmaxf(u_c.z + wB_c.z, 0.f), gv_c.z, acc1);
            acc0 = fmaf(fmaxf(u_c.w + wA_c.w, 0.f), gv_c.w, acc0);
            acc1 = fmaf(fmaxf(u_c.w + wB_c.w, 0.f), gv_c.w, acc1);
            u_c = u_n; gv_c = gv_n; wA_c = wA_n; wB_c = wB_n;
        }
        acc0 = fmaf(fmaxf(u_c.x + wA_c.x, 0.f), gv_c.x, acc0);
        acc1 = fmaf(fmaxf(u_c.x + wB_c.x, 0.f), gv_c.x, acc1);
        acc0 = fmaf(fmaxf(u_c.y + wA_c.y, 0.f), gv_c.y, acc0);
        acc1 = fmaf(fmaxf(u_c.y + wB_c.y, 0.f), gv_c.y, acc1);
        acc0 = fmaf(fmaxf(u_c.z + wA_c.z, 0.f), gv_c.z, acc0);
        acc1 = fmaf(fmaxf(u_c.z + wB_c.z, 0.f), gv_c.z, acc1);
        acc0 = fmaf(fmaxf(u_c.w + wA_c.w, 0.f), gv_c.w, acc0);
        acc1 = fmaf(fmaxf(u_c.w + wB_c.w, 0.f), gv_c.w, acc1);
    }
    int row = b * LQ + i0 + ti;
    float gA = acc0 + bias, gB = acc1 + bias;
    int jA = j0 + tj, jB = j0 + tj + 16;
    dec_out[(size_t)row * LQ + jA] = gA > 0.f ? 1.f : 0.f;
    dec_out[(size_t)row * LQ + jB] = gB > 0.f ? 1.f : 0.f;
    if (fabsf(gA) < 2e-2f) { int ix = atomicAdd(count, 1); if (ix < CAP) list[ix] = (row << 9) | jA; }
    if (fabsf(gB) < 2e-2f) { int ix = atomicAdd(count, 1); if (ix < CAP) list[ix] = (row << 9) | jB; }
}

// ---------------------------------------------------------------------------
// Exact fp64 gap for every flagged pair; writes fp64-sign decision.
// Tie (gap == 0) -> decision 0, matching np.argmax first-max semantics.
// ---------------------------------------------------------------------------
__global__ __launch_bounds__(256) void gap64_kernel(
    const double* __restrict__ U64, const double* __restrict__ W64,
    const float* __restrict__ W2, const float* __restrict__ b2,
    const int* __restrict__ count, const int* __restrict__ list,
    float* __restrict__ dec_out)
{
    int n = *count; if (n > CAP) n = CAP;
    int gw = (blockIdx.x * 256 + threadIdx.x) >> 6;
    int lane = threadIdx.x & 63;
    int nw = (gridDim.x * 256) >> 6;
    for (int idx = gw; idx < n; idx += nw) {
        int pij = list[idx];
        int j = pij & (LQ - 1);
        int row = pij >> 9;
        int b = row >> 9;
        const double* u = U64 + (size_t)row * H2;
        const double* w = W64 + ((size_t)(b * LQ) + j) * H2;
        double acc = 0.0;
        for (int g = lane; g < H2; g += 64) {
            double tv = u[g] + w[g];
            tv = tv > 0.0 ? tv : 0.0;
            acc = fma(tv, (double)W2[g * 2 + 1] - (double)W2[g * 2 + 0], acc);
        }
#pragma unroll
        for (int off = 32; off; off >>= 1) acc += __shfl_xor(acc, off, 64);
        if (lane == 0) {
            acc += (double)b2[1] - (double)b2[0];
            dec_out[(size_t)row * LQ + j] = acc > 0.0 ? 1.f : 0.f;
        }
    }
}

// ---------------------------------------------------------------------------
// Fused attention v2: grid 512 (32 bn x 16 i-tiles of 32 rows, 2 blocks/CU).
// ---------------------------------------------------------------------------
__global__ __launch_bounds__(256) void fused_attn(
    const float* __restrict__ q, const float* __restrict__ k,
    const float* __restrict__ v, const float* __restrict__ dec,
    float* __restrict__ attn, float* __restrict__ out)
{
    __shared__ __align__(16) float smem[10752];   // 43 KB, phase-overlaid
    float* qT = smem;            // [64][36]   kk-major
    float* kT = smem + 2304;     // [64][132]  kk-major
    float* Ps = smem;            // [32][65]   i-major  (PV phase)
    float* Vs = smem + 2112;     // [64][68]   j-major  (PV phase)
    int bid = blockIdx.x;
    int bn = bid >> 4;
    int i0 = (bid & 15) * 32;
    int b = bn >> 4;
    int t = threadIdx.x;

    {   // stage qT (transpose): i = t>>3, kkq = (t&7)+8*it
        int qi = t >> 3;
        const float* src = q + ((size_t)bn * LQ + i0 + qi) * DKk;
#pragma unroll
        for (int it = 0; it < 2; ++it) {
            int kkq = (t & 7) + it * 8;
            float4 t4 = *(const float4*)(src + kkq * 4);
            qT[(kkq * 4 + 0) * 36 + qi] = t4.x;
            qT[(kkq * 4 + 1) * 36 + qi] = t4.y;
            qT[(kkq * 4 + 2) * 36 + qi] = t4.z;
            qT[(kkq * 4 + 3) * 36 + qi] = t4.w;
        }
    }
    int tiq = t >> 5;            // 0..7  -> i = tiq*4 + r
    int tjq = t & 31;            // 0..31 -> j = c*128 + tjq*4 + cc
    float s[4][4][4];

#pragma unroll
    for (int c = 0; c < 4; ++c) {
        __syncthreads();
        {   // stage kT (transpose): j = (t>>2)+(it&1)*64, kkq = (t&3)+(it>>1)*4
            int kj = t >> 2;
#pragma unroll
            for (int it = 0; it < 8; ++it) {
                int jj = kj + (it & 1) * 64;
                int kkq = (t & 3) + (it >> 1) * 4;
                float4 t4 = *(const float4*)(k + ((size_t)bn * LQ + c * 128 + jj) * DKk + kkq * 4);
                kT[(kkq * 4 + 0) * 132 + jj] = t4.x;
                kT[(kkq * 4 + 1) * 132 + jj] = t4.y;
                kT[(kkq * 4 + 2) * 132 + jj] = t4.z;
                kT[(kkq * 4 + 3) * 132 + jj] = t4.w;
            }
        }
        __syncthreads();
        float acc[4][4] = {};
#pragma unroll 8
        for (int kk = 0; kk < 64; ++kk) {
            float4 a  = *(const float4*)&qT[kk * 36 + tiq * 4];
            float4 bb = *(const float4*)&kT[kk * 132 + tjq * 4];
            acc[0][0] = fmaf(a.x, bb.x, acc[0][0]); acc[0][1] = fmaf(a.x, bb.y, acc[0][1]);
            acc[0][2] = fmaf(a.x, bb.z, acc[0][2]); acc[0][3] = fmaf(a.x, bb.w, acc[0][3]);
            acc[1][0] = fmaf(a.y, bb.x, acc[1][0]); acc[1][1] = fmaf(a.y, bb.y, acc[1][1]);
            acc[1][2] = fmaf(a.y, bb.z, acc[1][2]); acc[1][3] = fmaf(a.y, bb.w, acc[1][3]);
            acc[2][0] = fmaf(a.z, bb.x, acc[2][0]); acc[2][1] = fmaf(a.z, bb.y, acc[2][1]);
            acc[2][2] = fmaf(a.z, bb.z, acc[2][2]); acc[2][3] = fmaf(a.z, bb.w, acc[2][3]);
            acc[3][0] = fmaf(a.w, bb.x, acc[3][0]); acc[3][1] = fmaf(a.w, bb.y, acc[3][1]);
            acc[3][2] = fmaf(a.w, bb.z, acc[3][2]); acc[3][3] = fmaf(a.w, bb.w, acc[3][3]);
        }
#pragma unroll
        for (int r = 0; r < 4; ++r) {
            float4 m4 = *(const float4*)&dec[((size_t)(b * LQ) + i0 + tiq * 4 + r) * LQ + c * 128 + tjq * 4];
            s[c][r][0] = m4.x != 0.f ? acc[r][0] * 0.125f : NEG_INF;
            s[c][r][1] = m4.y != 0.f ? acc[r][1] * 0.125f : NEG_INF;
            s[c][r][2] = m4.z != 0.f ? acc[r][2] * 0.125f : NEG_INF;
            s[c][r][3] = m4.w != 0.f ? acc[r][3] * 0.125f : NEG_INF;
        }
    }
    // softmax over 512 j per row (width-32 shuffle groups = tjq)
#pragma unroll
    for (int r = 0; r < 4; ++r) {
        float m = NEG_INF;
#pragma unroll
        for (int c = 0; c < 4; ++c)
#pragma unroll
            for (int cc = 0; cc < 4; ++cc) m = fmaxf(m, s[c][r][cc]);
#pragma unroll
        for (int off = 1; off < 32; off <<= 1) m = fmaxf(m, __shfl_xor(m, off, 32));
        float sum = 0.f;
#pragma unroll
        for (int c = 0; c < 4; ++c)
#pragma unroll
            for (int cc = 0; cc < 4; ++cc) {
                float e = __expf(s[c][r][cc] - m);
                s[c][r][cc] = e; sum += e;
            }
#pragma unroll
        for (int off = 1; off < 32; off <<= 1) sum += __shfl_xor(sum, off, 32);
        float inv = 1.f / sum;
#pragma unroll
        for (int c = 0; c < 4; ++c)
#pragma unroll
            for (int cc = 0; cc < 4; ++cc) s[c][r][cc] *= inv;
    }
#pragma unroll
    for (int c = 0; c < 4; ++c)
#pragma unroll
        for (int r = 0; r < 4; ++r) {
            float4 wv = make_float4(s[c][r][0], s[c][r][1], s[c][r][2], s[c][r][3]);
            *(float4*)&attn[((size_t)bn * LQ + i0 + tiq * 4 + r) * LQ + c * 128 + tjq * 4] = wv;
        }
    // ---- PV over eight 64-j chunks ----
    int tio = t >> 4;            // 0..15 -> i = tio*2 + rr
    int tdo = t & 15;            // 0..15 -> d = tdo*4
    float o[2][4] = {};
#pragma unroll
    for (int c8 = 0; c8 < 8; ++c8) {
        __syncthreads();
        if ((tjq >> 4) == (c8 & 1)) {      // this thread's s covers this chunk
            int jl4 = tjq & 15;
            int c = c8 >> 1;
#pragma unroll
            for (int r = 0; r < 4; ++r)
#pragma unroll
                for (int cc = 0; cc < 4; ++cc)
                    Ps[(tiq * 4 + r) * 65 + jl4 * 4 + cc] = s[c][r][cc];
        }
        {   // stage Vs: j = t>>2, dq = (t&3)+4*it
            int vj = t >> 2;
#pragma unroll
            for (int it = 0; it < 4; ++it) {
                int dq = (t & 3) + it * 4;
                *(float4*)&Vs[vj * 68 + dq * 4] =
                    *(const float4*)(v + ((size_t)bn * LQ + c8 * 64 + vj) * DVv + dq * 4);
            }
        }
        __syncthreads();
#pragma unroll 8
        for (int jj = 0; jj < 64; ++jj) {
            float p0 = Ps[(tio * 2 + 0) * 65 + jj];
            float p1 = Ps[(tio * 2 + 1) * 65 + jj];
            float4 v4 = *(const float4*)&Vs[jj * 68 + tdo * 4];
            o[0][0] = fmaf(p0, v4.x, o[0][0]); o[0][1] = fmaf(p0, v4.y, o[0][1]);
            o[0][2] = fmaf(p0, v4.z, o[0][2]); o[0][3] = fmaf(p0, v4.w, o[0][3]);
            o[1][0] = fmaf(p1, v4.x, o[1][0]); o[1][1] = fmaf(p1, v4.y, o[1][1]);
            o[1][2] = fmaf(p1, v4.z, o[1][2]); o[1][3] = fmaf(p1, v4.w, o[1][3]);
        }
    }
#pragma unroll
    for (int rr = 0; rr < 2; ++rr)
        *(float4*)&out[((size_t)bn * LQ + i0 + tio * 2 + rr) * DVv + tdo * 4] =
            make_float4(o[rr][0], o[rr][1], o[rr][2], o[rr][3]);
}

// ---------------------------------------------------------------------------
extern "C" void kernel_launch(void* const* d_in, const int* in_sizes, int n_in,
                              void* d_out, int out_size, void* d_ws, size_t ws_size,
                              hipStream_t stream)
{
    const float* q  = (const float*)d_in[0];
    const float* k  = (const float*)d_in[1];
    const float* v  = (const float*)d_in[2];
    const float* d0 = (const float*)d_in[3];
    const float* d1 = (const float*)d_in[4];
    const float* W1 = (const float*)d_in[5];
    const float* b1 = (const float*)d_in[6];
    const float* W2 = (const float*)d_in[7];
    const float* b2 = (const float*)d_in[8];

    float* out  = (float*)d_out;                                  // [2,16,512,64]
    float* attn = out + (size_t)BB * NN * LQ * DVv;               // [2,16,512,512]
    float* dec  = attn + (size_t)BB * NN * LQ * LQ;               // [2,1,512,512]

    // Scratch inside the attn region (32 MB); fully consumed before
    // fused_attn overwrites every attn element (same stream => ordered).
    char* scratch = (char*)attn;
    double* U64 = (double*)(scratch);                             // 0..2 MB
    double* W64 = (double*)(scratch + (2u << 20));                // 2..4 MB
    float*  U32 = (float*) (scratch + (4u << 20));                // 4..5 MB
    float*  W32 = (float*) (scratch + (5u << 20));                // 5..6 MB
    int* count  = (int*)   (scratch + (6u << 20));                // 4 B
    int* list   = (int*)   (scratch + (6u << 20) + 4096);         // 512 KB

    mlp_stage1<<<256, 256, 0, stream>>>(d0, d1, W1, b1, U64, W64, U32, W32, count);
    dec_full<<<1024, 256, 0, stream>>>(U32, W32, W2, b2, dec, count, list);
    gap64_kernel<<<256, 256, 0, stream>>>(U64, W64, W2, b2, count, list, dec);
    fused_attn<<<512, 256, 0, stream>>>(q, k, v, dec, attn, out);
}

// Round 4
// 175.676 us; speedup vs baseline: 1.3290x; 1.3023x over previous
//
#include <hip/hip_runtime.h>

#define BB 2
#define NN 16
#define LQ 512
#define DKk 64
#define DVv 64
#define DDd 128
#define H2 256
#define NEG_INF -1e9f
#define CAP 131072

// ---------------------------------------------------------------------------
// Stage 1 v2: 2 rows per block, grid 1024 (was 8 rows / 256 blocks = 1
// block/CU = 1 wave/SIMD, zero latency hiding on the W1 load chain).
// Now 4 blocks/CU, 16 waves/CU. Per-(row,g) fp64 chain unchanged
// (ascending f, single accumulator) -> bit-identical U/W outputs.
//   half 0: U[row,g] = b1[g] + sum_f d0[row,f]*W1[f,g]
//   half 1: W[row,g] =         sum_f d1[row,f]*W1[128+f,g]
// Block 0 thread 0 also zeroes the ambiguous-pair counter.
// ---------------------------------------------------------------------------
__global__ __launch_bounds__(256) void mlp_stage1(
    const float* __restrict__ d0, const float* __restrict__ d1,
    const float* __restrict__ W1, const float* __restrict__ b1,
    double* __restrict__ U64, double* __restrict__ W64,
    float* __restrict__ U32, float* __restrict__ W32,
    int* __restrict__ count)
{
    __shared__ float drow[2][DDd];
    int gid = blockIdx.x;            // half(2) x rowgroup(512)
    int half = gid >> 9;
    int r0 = (gid & 511) * 2;        // rows r0..r0+1 of 1024
    const float* din = half ? d1 : d0;
    int w1off = half ? DDd : 0;
    double* o64 = half ? W64 : U64;
    float* o32 = half ? W32 : U32;
    int t = threadIdx.x;
    if (gid == 0 && t == 0) *count = 0;
    // stage 2 rows x 128 f: 1 float/thread, coalesced
    drow[t >> 7][t & 127] = din[(size_t)(r0 + (t >> 7)) * DDd + (t & 127)];
    __syncthreads();
    int g = t;
    double acc[2] = {};
#pragma unroll 2
    for (int f = 0; f < DDd; f += 4) {
        double w0 = (double)W1[(w1off + f + 0) * H2 + g];
        double w1 = (double)W1[(w1off + f + 1) * H2 + g];
        double w2 = (double)W1[(w1off + f + 2) * H2 + g];
        double w3 = (double)W1[(w1off + f + 3) * H2 + g];
#pragma unroll
        for (int r = 0; r < 2; ++r) {
            float4 dr = *(const float4*)&drow[r][f];
            acc[r] = fma((double)dr.x, w0, acc[r]);
            acc[r] = fma((double)dr.y, w1, acc[r]);
            acc[r] = fma((double)dr.z, w2, acc[r]);
            acc[r] = fma((double)dr.w, w3, acc[r]);
        }
    }
    double bb = half ? 0.0 : (double)b1[g];
#pragma unroll
    for (int r = 0; r < 2; ++r) {
        double a = acc[r] + bb;
        o64[(size_t)(r0 + r) * H2 + g] = a;
        o32[(size_t)(r0 + r) * H2 + g] = (float)a;
    }
}

// ---------------------------------------------------------------------------
// dec_full v6: same tiling as v5 (16i x 32j x 256g, grid 1024, 4 blocks/CU)
// but the per-pair single-address global atomicAdd is GONE. Evidence it was
// the floor: R1/R3 dec kernels pinned at 73-75 us regardless of occupancy
// (17.8% vs 34.4%), and R2's trivial dec_combine (only kernel with the
// atomic) took 61 us at VALUBusy 0.29%. ~10K same-line device atomics x
// ~6 ns serialization = the observed 60-75 us.
// Now: flagged pairs -> LDS buffer via LDS atomic; ONE global atomicAdd per
// block reserves a slot range; coalesced list writes. Same list/count set
// semantics (order irrelevant to gap64). Decision math untouched.
// ---------------------------------------------------------------------------
__global__ __launch_bounds__(256, 4) void dec_full(
    const float* __restrict__ U32, const float* __restrict__ W32,
    const float* __restrict__ W2, const float* __restrict__ b2,
    float* __restrict__ dec_out, int* __restrict__ count, int* __restrict__ list)
{
    __shared__ __align__(16) float Us[16][68];    // [i][g-chunk 64]
    __shared__ __align__(16) float Ws[32][68];    // [j][g-chunk 64]
    __shared__ __align__(16) float gvs[H2];
    __shared__ int lbuf[512];                     // worst case: all pairs flagged
    __shared__ int lcnt, lbase;
    int bid = blockIdx.x;            // b(2) x it(32) x jt(16)
    int b  = bid >> 9;
    int i0 = ((bid >> 4) & 31) * 16;
    int j0 = (bid & 15) * 32;
    int t = threadIdx.x;
    gvs[t] = W2[t * 2 + 1] - W2[t * 2];
    if (t == 0) lcnt = 0;
    float bias = b2[1] - b2[0];
    int ti = t >> 4, tj = t & 15;    // i = i0+ti; j in {j0+tj, j0+tj+16}
    float acc0 = 0.f, acc1 = 0.f;
    for (int gc = 0; gc < H2; gc += 64) {
        __syncthreads();
        {   // stage U: 16 rows x 16 float4, 1/thread, coalesced
            int ui = t >> 4, gq = t & 15;
            *(float4*)&Us[ui][gq * 4] =
                *(const float4*)(U32 + ((size_t)(b * LQ) + i0 + ui) * H2 + gc + gq * 4);
        }
        {   // stage W: 32 rows x 16 float4, 2/thread, coalesced
            int wj = t >> 3, gq = t & 7;
            const float* src = W32 + ((size_t)(b * LQ) + j0 + wj) * H2 + gc;
            *(float4*)&Ws[wj][gq * 4] = *(const float4*)(src + gq * 4);
            *(float4*)&Ws[wj][(gq + 8) * 4] = *(const float4*)(src + (gq + 8) * 4);
        }
        __syncthreads();
        float4 u_c  = *(const float4*)&Us[ti][0];
        float4 gv_c = *(const float4*)&gvs[gc];
        float4 wA_c = *(const float4*)&Ws[tj][0];
        float4 wB_c = *(const float4*)&Ws[tj + 16][0];
#pragma unroll 5
        for (int gg = 0; gg < 60; gg += 4) {
            float4 u_n  = *(const float4*)&Us[ti][gg + 4];
            float4 gv_n = *(const float4*)&gvs[gc + gg + 4];
            float4 wA_n = *(const float4*)&Ws[tj][gg + 4];
            float4 wB_n = *(const float4*)&Ws[tj + 16][gg + 4];
            acc0 = fmaf(fmaxf(u_c.x + wA_c.x, 0.f), gv_c.x, acc0);
            acc1 = fmaf(fmaxf(u_c.x + wB_c.x, 0.f), gv_c.x, acc1);
            acc0 = fmaf(fmaxf(u_c.y + wA_c.y, 0.f), gv_c.y, acc0);
            acc1 = fmaf(fmaxf(u_c.y + wB_c.y, 0.f), gv_c.y, acc1);
            acc0 = fmaf(fmaxf(u_c.z + wA_c.z, 0.f), gv_c.z, acc0);
            acc1 = fmaf(fmaxf(u_c.z + wB_c.z, 0.f), gv_c.z, acc1);
            acc0 = fmaf(fmaxf(u_c.w + wA_c.w, 0.f), gv_c.w, acc0);
            acc1 = fmaf(fmaxf(u_c.w + wB_c.w, 0.f), gv_c.w, acc1);
            u_c = u_n; gv_c = gv_n; wA_c = wA_n; wB_c = wB_n;
        }
        acc0 = fmaf(fmaxf(u_c.x + wA_c.x, 0.f), gv_c.x, acc0);
        acc1 = fmaf(fmaxf(u_c.x + wB_c.x, 0.f), gv_c.x, acc1);
        acc0 = fmaf(fmaxf(u_c.y + wA_c.y, 0.f), gv_c.y, acc0);
        acc1 = fmaf(fmaxf(u_c.y + wB_c.y, 0.f), gv_c.y, acc1);
        acc0 = fmaf(fmaxf(u_c.z + wA_c.z, 0.f), gv_c.z, acc0);
        acc1 = fmaf(fmaxf(u_c.z + wB_c.z, 0.f), gv_c.z, acc1);
        acc0 = fmaf(fmaxf(u_c.w + wA_c.w, 0.f), gv_c.w, acc0);
        acc1 = fmaf(fmaxf(u_c.w + wB_c.w, 0.f), gv_c.w, acc1);
    }
    int row = b * LQ + i0 + ti;
    float gA = acc0 + bias, gB = acc1 + bias;
    int jA = j0 + tj, jB = j0 + tj + 16;
    dec_out[(size_t)row * LQ + jA] = gA > 0.f ? 1.f : 0.f;
    dec_out[(size_t)row * LQ + jB] = gB > 0.f ? 1.f : 0.f;
    if (fabsf(gA) < 2e-2f) { int lx = atomicAdd(&lcnt, 1); lbuf[lx] = (row << 9) | jA; }
    if (fabsf(gB) < 2e-2f) { int lx = atomicAdd(&lcnt, 1); lbuf[lx] = (row << 9) | jB; }
    __syncthreads();
    if (t == 0 && lcnt > 0) lbase = atomicAdd(count, lcnt);
    __syncthreads();
    for (int x = t; x < lcnt; x += 256) {
        int ix = lbase + x;
        if (ix < CAP) list[ix] = lbuf[x];
    }
}

// ---------------------------------------------------------------------------
// Exact fp64 gap for every flagged pair; writes fp64-sign decision.
// Tie (gap == 0) -> decision 0, matching np.argmax first-max semantics.
// ---------------------------------------------------------------------------
__global__ __launch_bounds__(256) void gap64_kernel(
    const double* __restrict__ U64, const double* __restrict__ W64,
    const float* __restrict__ W2, const float* __restrict__ b2,
    const int* __restrict__ count, const int* __restrict__ list,
    float* __restrict__ dec_out)
{
    int n = *count; if (n > CAP) n = CAP;
    int gw = (blockIdx.x * 256 + threadIdx.x) >> 6;
    int lane = threadIdx.x & 63;
    int nw = (gridDim.x * 256) >> 6;
    for (int idx = gw; idx < n; idx += nw) {
        int pij = list[idx];
        int j = pij & (LQ - 1);
        int row = pij >> 9;
        int b = row >> 9;
        const double* u = U64 + (size_t)row * H2;
        const double* w = W64 + ((size_t)(b * LQ) + j) * H2;
        double acc = 0.0;
        for (int g = lane; g < H2; g += 64) {
            double tv = u[g] + w[g];
            tv = tv > 0.0 ? tv : 0.0;
            acc = fma(tv, (double)W2[g * 2 + 1] - (double)W2[g * 2 + 0], acc);
        }
#pragma unroll
        for (int off = 32; off; off >>= 1) acc += __shfl_xor(acc, off, 64);
        if (lane == 0) {
            acc += (double)b2[1] - (double)b2[0];
            dec_out[(size_t)row * LQ + j] = acc > 0.0 ? 1.f : 0.f;
        }
    }
}

// ---------------------------------------------------------------------------
// Fused attention v2: grid 512 (32 bn x 16 i-tiles of 32 rows, 2 blocks/CU).
// ---------------------------------------------------------------------------
__global__ __launch_bounds__(256) void fused_attn(
    const float* __restrict__ q, const float* __restrict__ k,
    const float* __restrict__ v, const float* __restrict__ dec,
    float* __restrict__ attn, float* __restrict__ out)
{
    __shared__ __align__(16) float smem[10752];   // 43 KB, phase-overlaid
    float* qT = smem;            // [64][36]   kk-major
    float* kT = smem + 2304;     // [64][132]  kk-major
    float* Ps = smem;            // [32][65]   i-major  (PV phase)
    float* Vs = smem + 2112;     // [64][68]   j-major  (PV phase)
    int bid = blockIdx.x;
    int bn = bid >> 4;
    int i0 = (bid & 15) * 32;
    int b = bn >> 4;
    int t = threadIdx.x;

    {   // stage qT (transpose): i = t>>3, kkq = (t&7)+8*it
        int qi = t >> 3;
        const float* src = q + ((size_t)bn * LQ + i0 + qi) * DKk;
#pragma unroll
        for (int it = 0; it < 2; ++it) {
            int kkq = (t & 7) + it * 8;
            float4 t4 = *(const float4*)(src + kkq * 4);
            qT[(kkq * 4 + 0) * 36 + qi] = t4.x;
            qT[(kkq * 4 + 1) * 36 + qi] = t4.y;
            qT[(kkq * 4 + 2) * 36 + qi] = t4.z;
            qT[(kkq * 4 + 3) * 36 + qi] = t4.w;
        }
    }
    int tiq = t >> 5;            // 0..7  -> i = tiq*4 + r
    int tjq = t & 31;            // 0..31 -> j = c*128 + tjq*4 + cc
    float s[4][4][4];

#pragma unroll
    for (int c = 0; c < 4; ++c) {
        __syncthreads();
        {   // stage kT (transpose): j = (t>>2)+(it&1)*64, kkq = (t&3)+(it>>1)*4
            int kj = t >> 2;
#pragma unroll
            for (int it = 0; it < 8; ++it) {
                int jj = kj + (it & 1) * 64;
                int kkq = (t & 3) + (it >> 1) * 4;
                float4 t4 = *(const float4*)(k + ((size_t)bn * LQ + c * 128 + jj) * DKk + kkq * 4);
                kT[(kkq * 4 + 0) * 132 + jj] = t4.x;
                kT[(kkq * 4 + 1) * 132 + jj] = t4.y;
                kT[(kkq * 4 + 2) * 132 + jj] = t4.z;
                kT[(kkq * 4 + 3) * 132 + jj] = t4.w;
            }
        }
        __syncthreads();
        float acc[4][4] = {};
#pragma unroll 8
        for (int kk = 0; kk < 64; ++kk) {
            float4 a  = *(const float4*)&qT[kk * 36 + tiq * 4];
            float4 bb = *(const float4*)&kT[kk * 132 + tjq * 4];
            acc[0][0] = fmaf(a.x, bb.x, acc[0][0]); acc[0][1] = fmaf(a.x, bb.y, acc[0][1]);
            acc[0][2] = fmaf(a.x, bb.z, acc[0][2]); acc[0][3] = fmaf(a.x, bb.w, acc[0][3]);
            acc[1][0] = fmaf(a.y, bb.x, acc[1][0]); acc[1][1] = fmaf(a.y, bb.y, acc[1][1]);
            acc[1][2] = fmaf(a.y, bb.z, acc[1][2]); acc[1][3] = fmaf(a.y, bb.w, acc[1][3]);
            acc[2][0] = fmaf(a.z, bb.x, acc[2][0]); acc[2][1] = fmaf(a.z, bb.y, acc[2][1]);
            acc[2][2] = fmaf(a.z, bb.z, acc[2][2]); acc[2][3] = fmaf(a.z, bb.w, acc[2][3]);
            acc[3][0] = fmaf(a.w, bb.x, acc[3][0]); acc[3][1] = fmaf(a.w, bb.y, acc[3][1]);
            acc[3][2] = fmaf(a.w, bb.z, acc[3][2]); acc[3][3] = fmaf(a.w, bb.w, acc[3][3]);
        }
#pragma unroll
        for (int r = 0; r < 4; ++r) {
            float4 m4 = *(const float4*)&dec[((size_t)(b * LQ) + i0 + tiq * 4 + r) * LQ + c * 128 + tjq * 4];
            s[c][r][0] = m4.x != 0.f ? acc[r][0] * 0.125f : NEG_INF;
            s[c][r][1] = m4.y != 0.f ? acc[r][1] * 0.125f : NEG_INF;
            s[c][r][2] = m4.z != 0.f ? acc[r][2] * 0.125f : NEG_INF;
            s[c][r][3] = m4.w != 0.f ? acc[r][3] * 0.125f : NEG_INF;
        }
    }
    // softmax over 512 j per row (width-32 shuffle groups = tjq)
#pragma unroll
    for (int r = 0; r < 4; ++r) {
        float m = NEG_INF;
#pragma unroll
        for (int c = 0; c < 4; ++c)
#pragma unroll
            for (int cc = 0; cc < 4; ++cc) m = fmaxf(m, s[c][r][cc]);
#pragma unroll
        for (int off = 1; off < 32; off <<= 1) m = fmaxf(m, __shfl_xor(m, off, 32));
        float sum = 0.f;
#pragma unroll
        for (int c = 0; c < 4; ++c)
#pragma unroll
            for (int cc = 0; cc < 4; ++cc) {
                float e = __expf(s[c][r][cc] - m);
                s[c][r][cc] = e; sum += e;
            }
#pragma unroll
        for (int off = 1; off < 32; off <<= 1) sum += __shfl_xor(sum, off, 32);
        float inv = 1.f / sum;
#pragma unroll
        for (int c = 0; c < 4; ++c)
#pragma unroll
            for (int cc = 0; cc < 4; ++cc) s[c][r][cc] *= inv;
    }
#pragma unroll
    for (int c = 0; c < 4; ++c)
#pragma unroll
        for (int r = 0; r < 4; ++r) {
            float4 wv = make_float4(s[c][r][0], s[c][r][1], s[c][r][2], s[c][r][3]);
            *(float4*)&attn[((size_t)bn * LQ + i0 + tiq * 4 + r) * LQ + c * 128 + tjq * 4] = wv;
        }
    // ---- PV over eight 64-j chunks ----
    int tio = t >> 4;            // 0..15 -> i = tio*2 + rr
    int tdo = t & 15;            // 0..15 -> d = tdo*4
    float o[2][4] = {};
#pragma unroll
    for (int c8 = 0; c8 < 8; ++c8) {
        __syncthreads();
        if ((tjq >> 4) == (c8 & 1)) {      // this thread's s covers this chunk
            int jl4 = tjq & 15;
            int c = c8 >> 1;
#pragma unroll
            for (int r = 0; r < 4; ++r)
#pragma unroll
                for (int cc = 0; cc < 4; ++cc)
                    Ps[(tiq * 4 + r) * 65 + jl4 * 4 + cc] = s[c][r][cc];
        }
        {   // stage Vs: j = t>>2, dq = (t&3)+4*it
            int vj = t >> 2;
#pragma unroll
            for (int it = 0; it < 4; ++it) {
                int dq = (t & 3) + it * 4;
                *(float4*)&Vs[vj * 68 + dq * 4] =
                    *(const float4*)(v + ((size_t)bn * LQ + c8 * 64 + vj) * DVv + dq * 4);
            }
        }
        __syncthreads();
#pragma unroll 8
        for (int jj = 0; jj < 64; ++jj) {
            float p0 = Ps[(tio * 2 + 0) * 65 + jj];
            float p1 = Ps[(tio * 2 + 1) * 65 + jj];
            float4 v4 = *(const float4*)&Vs[jj * 68 + tdo * 4];
            o[0][0] = fmaf(p0, v4.x, o[0][0]); o[0][1] = fmaf(p0, v4.y, o[0][1]);
            o[0][2] = fmaf(p0, v4.z, o[0][2]); o[0][3] = fmaf(p0, v4.w, o[0][3]);
            o[1][0] = fmaf(p1, v4.x, o[1][0]); o[1][1] = fmaf(p1, v4.y, o[1][1]);
            o[1][2] = fmaf(p1, v4.z, o[1][2]); o[1][3] = fmaf(p1, v4.w, o[1][3]);
        }
    }
#pragma unroll
    for (int rr = 0; rr < 2; ++rr)
        *(float4*)&out[((size_t)bn * LQ + i0 + tio * 2 + rr) * DVv + tdo * 4] =
            make_float4(o[rr][0], o[rr][1], o[rr][2], o[rr][3]);
}

// ---------------------------------------------------------------------------
extern "C" void kernel_launch(void* const* d_in, const int* in_sizes, int n_in,
                              void* d_out, int out_size, void* d_ws, size_t ws_size,
                              hipStream_t stream)
{
    const float* q  = (const float*)d_in[0];
    const float* k  = (const float*)d_in[1];
    const float* v  = (const float*)d_in[2];
    const float* d0 = (const float*)d_in[3];
    const float* d1 = (const float*)d_in[4];
    const float* W1 = (const float*)d_in[5];
    const float* b1 = (const float*)d_in[6];
    const float* W2 = (const float*)d_in[7];
    const float* b2 = (const float*)d_in[8];

    float* out  = (float*)d_out;                                  // [2,16,512,64]
    float* attn = out + (size_t)BB * NN * LQ * DVv;               // [2,16,512,512]
    float* dec  = attn + (size_t)BB * NN * LQ * LQ;               // [2,1,512,512]

    // Scratch inside the attn region (32 MB); fully consumed before
    // fused_attn overwrites every attn element (same stream => ordered).
    char* scratch = (char*)attn;
    double* U64 = (double*)(scratch);                             // 0..2 MB
    double* W64 = (double*)(scratch + (2u << 20));                // 2..4 MB
    float*  U32 = (float*) (scratch + (4u << 20));                // 4..5 MB
    float*  W32 = (float*) (scratch + (5u << 20));                // 5..6 MB
    int* count  = (int*)   (scratch + (6u << 20));                // 4 B
    int* list   = (int*)   (scratch + (6u << 20) + 4096);         // 512 KB

    mlp_stage1<<<1024, 256, 0, stream>>>(d0, d1, W1, b1, U64, W64, U32, W32, count);
    dec_full<<<1024, 256, 0, stream>>>(U32, W32, W2, b2, dec, count, list);
    gap64_kernel<<<256, 256, 0, stream>>>(U64, W64, W2, b2, count, list, dec);
    fused_attn<<<512, 256, 0, stream>>>(q, k, v, dec, attn, out);
}